// Round 19
// baseline (871.836 us; speedup 1.0000x reference)
//
#include <hip/hip_runtime.h>
#include <math.h>

#define NROWS 65536
#define D 256
#define K 1024
#define CAP 8
#define SCAP 8
#define EPS 1e-3f

// d_out offsets (floats)
#define OFF_Q     0
#define OFF_LOSS  16777216
#define OFF_IDX   16777217
#define OFF_CS    16842753
#define OFF_EMAW  16843777
#define OFF_UPD   17105921

// ws offsets (bytes)
#define WS_HIST     0          // 1024 int (memset 0, together with GC)
#define WS_GC       4096       // 4 int
#define WS_OFFS     8192       // 1024 int
#define WS_CURS     12288      // 1024 int
#define WS_UOFFS    16384      // 1025 int (unit prefix; [1024]=total U)
#define WS_UNITS    20736      // 2048 int ((j<<10)|c)
#define WS_IDX      29184      // 65536 int
#define WS_CNT      291328     // 65536 int
#define WS_WROWS    553472     // 65536 int
#define WS_ROWIDS   815616     // 65536 int
#define WS_SQX      1077760    // 65536 f32
#define WS_SQE      1339904    // 1024 f32
#define WS_LOSSP    1344000    // 2048 double (zeroed by k_prefix)
#define WS_EBT      1360384    // 8*1024*32 ushort (bf16, k-chunk-major)
#define WS_CAND     1884672    // 65536*8 int
#define WS_UDW      3981824    // 2048*256 f32 (per-unit dw partials)
#define WS_PACK     3981824    //   alias: 65536 u64 (init by k_screen; dead before k_dw)
// ends 6078976

typedef __attribute__((ext_vector_type(8))) short short8;
typedef __attribute__((ext_vector_type(8))) unsigned short ushort8;
typedef __attribute__((ext_vector_type(4))) float f32x4;

__device__ __forceinline__ unsigned short f2b(float f) {   // RNE f32->bf16
    unsigned u = __builtin_bit_cast(unsigned, f);
    return (unsigned short)((u + 0x7fffu + ((u >> 16) & 1u)) >> 16);
}

// exact reference-order dot: single f32 acc, fmaf over k=0..255 ascending.
__device__ __forceinline__ float dot_chain(const float4* __restrict__ xr,
                                           const float4* __restrict__ er) {
#pragma clang fp contract(off)
    float acc = 0.f;
#pragma unroll
    for (int g = 0; g < 8; ++g) {
        float4 xa[8], ea[8];
#pragma unroll
        for (int m = 0; m < 8; ++m) { xa[m] = xr[g * 8 + m]; ea[m] = er[g * 8 + m]; }
#pragma unroll
        for (int m = 0; m < 8; ++m) {
            acc = __builtin_fmaf(xa[m].x, ea[m].x, acc);
            acc = __builtin_fmaf(xa[m].y, ea[m].y, acc);
            acc = __builtin_fmaf(xa[m].z, ea[m].z, acc);
            acc = __builtin_fmaf(xa[m].w, ea[m].w, acc);
        }
    }
    return acc;
}

// ---------------- K0b: codebook -> bf16 k-chunk-major [8][1024][32] + fused sqe ----------------
__global__ __launch_bounds__(256) void k_cvt(const float* __restrict__ ew,
                                             unsigned short* __restrict__ ebt,
                                             float* __restrict__ sqe)
{
#pragma clang fp contract(off)
    int t = blockIdx.x * 256 + threadIdx.x;   // 0..8191
    int code = t >> 3, kc = t & 7;
    const float4* src = (const float4*)&ew[(size_t)code * 256 + kc * 32];
    unsigned short* dst = &ebt[((size_t)kc * 1024 + code) * 32];
    float4 f[8];
#pragma unroll
    for (int j = 0; j < 8; ++j) f[j] = src[j];
#pragma unroll
    for (int j = 0; j < 8; ++j) {
        ushort4 o;
        o.x = f2b(f[j].x); o.y = f2b(f[j].y); o.z = f2b(f[j].z); o.w = f2b(f[j].w);
        *(ushort4*)&dst[j * 4] = o;
    }
    float p[16];
#pragma unroll
    for (int m = 0; m < 4; ++m) {
        p[4*m+0] = f[m].x * f[m].x + f[m+4].x * f[m+4].x;
        p[4*m+1] = f[m].y * f[m].y + f[m+4].y * f[m+4].y;
        p[4*m+2] = f[m].z * f[m].z + f[m+4].z * f[m+4].z;
        p[4*m+3] = f[m].w * f[m].w + f[m+4].w * f[m+4].w;
    }
    float V[16];
#pragma unroll
    for (int l2 = 0; l2 < 16; ++l2) {
        float q = p[l2] + __shfl_xor(p[l2], 1);
        V[l2] = q + __shfl_xor(q, 2);
    }
    float t8[8];
#pragma unroll
    for (int l2 = 0; l2 < 8; ++l2) t8[l2] = V[l2] + V[l2 + 8];
    float u4[4];
#pragma unroll
    for (int l2 = 0; l2 < 4; ++l2) u4[l2] = t8[l2] + t8[l2 + 4];
    float h = (u4[0] + u4[2]) + (u4[1] + u4[3]);
    float sq = h + __shfl_xor(h, 4);
    if (kc == 0) sqe[code] = sq;
}

// ---------------- K1: MFMA bf16 screen, 32 rows / 256 thr / 4 waves ----------------
// LDS = 19712 B <= 20 KB so 8 blocks/CU co-resident (grid 2048 = exactly 8/CU;
// at 22 KB only 7 fit -> 1-block tail generation per CU = the 37%-occupancy stall).
__global__ __launch_bounds__(256) void k_screen(
    const float* __restrict__ x, const unsigned short* __restrict__ ebt,
    const float* __restrict__ sqe, float* __restrict__ sqx_out,
    int* __restrict__ cnt, int* __restrict__ cand,
    int* __restrict__ idx_out, float* __restrict__ idxf_out,
    int* __restrict__ hist, int* __restrict__ wrows, int* __restrict__ gc,
    unsigned long long* __restrict__ packed)
{
    __shared__ unsigned short xs[32][264];   // 16896 B
    __shared__ float red[32][4];             // 512 B
    __shared__ int lcnt[32];                 // 128 B
    __shared__ float gmin[32];               // 128 B
    __shared__ int scand_c[32][SCAP];        // 1024 B
    __shared__ float scand_s[32][SCAP];      // 1024 B

    const int tid = threadIdx.x;
    const int wn = tid >> 6;
    const int l = tid & 63;
    const int row0 = blockIdx.x * 32;

    if (tid < 32) { lcnt[tid] = 0; gmin[tid] = 3.4e38f; }

    {
        const int row = tid >> 3, kq8 = tid & 7;
        const float4* src = (const float4*)&x[(size_t)(row0 + row) * 256 + kq8 * 32];
        float4 f[8];
#pragma unroll
        for (int j = 0; j < 8; ++j) f[j] = src[j];
#pragma unroll
        for (int j = 0; j < 8; ++j) {
            ushort4 o;
            o.x = f2b(f[j].x); o.y = f2b(f[j].y); o.z = f2b(f[j].z); o.w = f2b(f[j].w);
            *(ushort4*)&xs[row][kq8 * 32 + j * 4] = o;
        }
        float p[16];
#pragma unroll
        for (int m = 0; m < 4; ++m) {
            p[4*m+0] = f[m].x * f[m].x + f[m+4].x * f[m+4].x;
            p[4*m+1] = f[m].y * f[m].y + f[m+4].y * f[m+4].y;
            p[4*m+2] = f[m].z * f[m].z + f[m+4].z * f[m+4].z;
            p[4*m+3] = f[m].w * f[m].w + f[m+4].w * f[m+4].w;
        }
        float V[16];
#pragma unroll
        for (int l2 = 0; l2 < 16; ++l2) {
            float q = p[l2] + __shfl_xor(p[l2], 1);
            V[l2] = q + __shfl_xor(q, 2);
        }
        float t8[8];
#pragma unroll
        for (int l2 = 0; l2 < 8; ++l2) t8[l2] = V[l2] + V[l2 + 8];
        float u4[4];
#pragma unroll
        for (int l2 = 0; l2 < 4; ++l2) u4[l2] = t8[l2] + t8[l2 + 4];
        float h = (u4[0] + u4[2]) + (u4[1] + u4[3]);
        float sq = h + __shfl_xor(h, 4);
        if (kq8 == 0) sqx_out[row0 + row] = sq;
    }
    __syncthreads();

#pragma unroll 1
    for (int ct = 0; ct < 4; ++ct) {
        f32x4 acc[2][4];
#pragma unroll
        for (int mt = 0; mt < 2; ++mt)
#pragma unroll
            for (int nt = 0; nt < 4; ++nt) acc[mt][nt] = (f32x4)0.f;

#pragma unroll 2
        for (int kc = 0; kc < 8; ++kc) {
            short8 a[2], b[4];
#pragma unroll
            for (int nt = 0; nt < 4; ++nt)
                b[nt] = *(const short8*)&ebt[
                    ((size_t)kc * 1024 + ct * 256 + wn * 64 + nt * 16 + (l & 15)) * 32
                    + (l >> 4) * 8];
#pragma unroll
            for (int mt = 0; mt < 2; ++mt)
                a[mt] = *(const short8*)&xs[mt * 16 + (l & 15)][kc * 32 + (l >> 4) * 8];
#pragma unroll
            for (int mt = 0; mt < 2; ++mt)
#pragma unroll
                for (int nt = 0; nt < 4; ++nt)
                    acc[mt][nt] = __builtin_amdgcn_mfma_f32_16x16x32_bf16(
                        a[mt], b[nt], acc[mt][nt], 0, 0, 0);
        }

        float sev[4];
#pragma unroll
        for (int nt = 0; nt < 4; ++nt)
            sev[nt] = sqe[ct * 256 + wn * 64 + nt * 16 + (l & 15)];

        float s_[2][16];
        float lmin[2][4];
#pragma unroll
        for (int mt = 0; mt < 2; ++mt) {
#pragma unroll
            for (int q = 0; q < 4; ++q) lmin[mt][q] = 3.4e38f;
#pragma unroll
            for (int nt = 0; nt < 4; ++nt)
#pragma unroll
                for (int q = 0; q < 4; ++q) {
                    float sv = sev[nt] - 2.0f * acc[mt][nt][q];
                    s_[mt][nt * 4 + q] = sv;
                    lmin[mt][q] = fminf(lmin[mt][q], sv);
                }
        }
#pragma unroll
        for (int mt = 0; mt < 2; ++mt)
#pragma unroll
            for (int q = 0; q < 4; ++q) {
                float v = lmin[mt][q];
#pragma unroll
                for (int m = 1; m < 16; m <<= 1) v = fminf(v, __shfl_xor(v, m));
                if ((l & 15) == 0) red[mt * 16 + (l >> 4) * 4 + q][wn] = v;
            }
        __syncthreads();
        if (tid < 32)
            gmin[tid] = fminf(gmin[tid],
                              fminf(fminf(red[tid][0], red[tid][1]),
                                    fminf(red[tid][2], red[tid][3])));
#pragma unroll
        for (int mt = 0; mt < 2; ++mt)
#pragma unroll
            for (int q = 0; q < 4; ++q) {
                const int rw = mt * 16 + (l >> 4) * 4 + q;
                const float rm = fminf(fminf(red[rw][0], red[rw][1]),
                                       fminf(red[rw][2], red[rw][3])) + EPS;
                if (__any(lmin[mt][q] <= rm)) {
#pragma unroll
                    for (int nt = 0; nt < 4; ++nt) {
                        float s = s_[mt][nt * 4 + q];
                        if (s <= rm) {
                            int c = ct * 256 + wn * 64 + nt * 16 + (l & 15);
                            int slot = atomicAdd(&lcnt[rw], 1);
                            if (slot < SCAP) { scand_c[rw][slot] = c; scand_s[rw][slot] = s; }
                        }
                    }
                }
            }
        __syncthreads();
    }
    if (tid < 32) {
        const int row = row0 + tid;
        const int m = lcnt[tid];
        if (m > SCAP) {
            cnt[row] = CAP + 1;   // defensive: exact full scan in k_rescore
            packed[row] = ~0ULL;
            int p0 = atomicAdd(&gc[0], 1);
            wrows[p0] = row;
        } else {
            const float thr = gmin[tid] + EPS;
            int n = 0;
            int keep[CAP];
            for (int j = 0; j < m; ++j) {
                if (scand_s[tid][j] <= thr) {
                    if (n < CAP) keep[n] = scand_c[tid][j];
                    ++n;
                }
            }
            cnt[row] = n;
            if (n == 1) {
                idx_out[row] = keep[0];
                idxf_out[row] = (float)keep[0];
                atomicAdd(&hist[keep[0]], 1);
            } else {
                packed[row] = ~0ULL;
                int p0 = atomicAdd(&gc[0], 1);
                wrows[p0] = row;
                const int mm = n < CAP ? n : CAP;
                for (int s = 0; s < mm; ++s)
                    cand[(size_t)row * CAP + s] = keep[s];
            }
        }
    }
}

// ---------------- K1b: pair-per-lane exact rescore -> packed atomicMin ----------------
__global__ __launch_bounds__(256) void k_rescore(
    const float* __restrict__ x, const float* __restrict__ ew,
    const float* __restrict__ sqx, const float* __restrict__ sqe,
    const int* __restrict__ cnt, const int* __restrict__ cand,
    const int* __restrict__ wrows, const int* __restrict__ gc,
    unsigned long long* __restrict__ packed)
{
#pragma clang fp contract(off)
    const int nw = gc[0];
    const int total = nw * CAP;
    for (int i = blockIdx.x * 256 + threadIdx.x; i < total; i += gridDim.x * 256) {
        const int row = wrows[i >> 3];
        const int slot = i & (CAP - 1);
        const int n = cnt[row];
        const float sxr = sqx[row];
        const float4* xr = (const float4*)&x[(size_t)row * 256];
        if (n >= 2 && n <= CAP) {
            if (slot >= n) continue;
            const int c = cand[(size_t)row * CAP + slot];
            float acc = dot_chain(xr, (const float4*)&ew[(size_t)c * 256]);
            float d = (sxr - 2.0f * acc) + sqe[c];
            unsigned long long key =
                ((unsigned long long)__builtin_bit_cast(unsigned, d) << 32) | (unsigned)c;
            atomicMin(&packed[row], key);
        } else {
            float bd = 3.4e38f; int bc = 0x7fffffff;
            for (int c = slot; c < K; c += CAP) {
                float acc = dot_chain(xr, (const float4*)&ew[(size_t)c * 256]);
                float d = (sxr - 2.0f * acc) + sqe[c];
                if (d < bd || (d == bd && c < bc)) { bd = d; bc = c; }
            }
            unsigned long long key =
                ((unsigned long long)__builtin_bit_cast(unsigned, bd) << 32) | (unsigned)bc;
            atomicMin(&packed[row], key);
        }
    }
}

// ---------------- K1c: resolve worklist rows -> idx + hist ----------------
__global__ __launch_bounds__(256) void k_resolve(
    const int* __restrict__ wrows, const int* __restrict__ gc,
    const unsigned long long* __restrict__ packed,
    int* __restrict__ idx_out, float* __restrict__ idxf_out, int* __restrict__ hist)
{
    const int nw = gc[0];
    for (int i = blockIdx.x * 256 + threadIdx.x; i < nw; i += gridDim.x * 256) {
        const int row = wrows[i];
        const int c = (int)(packed[row] & 0xffffffffu);
        idx_out[row] = c;
        idxf_out[row] = (float)c;
        atomicAdd(&hist[c], 1);
    }
}

// ---------------- K2: prefix sums (codes + work units) + zero loss partials ----------------
__global__ __launch_bounds__(1024) void k_prefix(
    const int* __restrict__ hist, int* __restrict__ offs, int* __restrict__ curs,
    int* __restrict__ uoffs, int* __restrict__ units, double* __restrict__ lossp)
{
    __shared__ int tmp[1024];
    const int tid = threadIdx.x;
    const int h = hist[tid];
    tmp[tid] = h;
    __syncthreads();
    for (int off = 1; off < 1024; off <<= 1) {
        int v = (tid >= off) ? tmp[tid - off] : 0;
        __syncthreads();
        tmp[tid] += v;
        __syncthreads();
    }
    int ex = tmp[tid] - h;
    offs[tid] = ex;
    curs[tid] = ex;
    __syncthreads();
    const int uc = (h + 63) >> 6;
    tmp[tid] = uc;
    __syncthreads();
    for (int off = 1; off < 1024; off <<= 1) {
        int v = (tid >= off) ? tmp[tid - off] : 0;
        __syncthreads();
        tmp[tid] += v;
        __syncthreads();
    }
    const int uex = tmp[tid] - uc;
    uoffs[tid] = uex;
    if (tid == 1023) uoffs[1024] = tmp[1023];
    lossp[tid] = 0.0;
    lossp[tid + 1024] = 0.0;
    for (int j = 0; j < uc; ++j)
        units[uex + j] = (j << 10) | tid;
}

// ---------------- K3: fill row-id bins ----------------
__global__ __launch_bounds__(256) void k_fill(
    const int* __restrict__ idx_in, int* __restrict__ curs, int* __restrict__ rowids)
{
    int r = blockIdx.x * 256 + threadIdx.x;
    int c = idx_in[r];
    int slot = atomicAdd(&curs[c], 1);
    rowids[slot] = r;
}

// ---------------- K4: per-UNIT dw partial, 8-wide batched gather ----------------
__global__ __launch_bounds__(256) void k_dw(
    const float* __restrict__ x, const float* __restrict__ ew,
    const int* __restrict__ hist, const int* __restrict__ offs,
    const int* __restrict__ uoffs, const int* __restrict__ units,
    const int* __restrict__ rowids,
    float* __restrict__ q_out, float* __restrict__ udw, double* __restrict__ lossp)
{
    const int U = uoffs[1024];
    const int b = blockIdx.x;
    if (b >= U) return;
    const int u = units[b];
    const int c = u & 1023;
    const int j = u >> 10;
    const int tid = threadIdx.x;
    const int n = hist[c];
    const int start = j << 6;
    const int len = min(64, n - start);
    const int base = offs[c] + start;
    __shared__ int rid[64];
    if (tid < 64 && tid < len) rid[tid] = rowids[base + tid];
    __syncthreads();
    const float ev = ew[(size_t)c * 256 + tid];
    float acc = 0.f;
    float lsum = 0.f;
    int i = 0;
    for (; i + 8 <= len; i += 8) {
        float xv[8];
#pragma unroll
        for (int m = 0; m < 8; ++m)
            xv[m] = x[(size_t)rid[i + m] * 256 + tid];
#pragma unroll
        for (int m = 0; m < 8; ++m) {
            q_out[(size_t)rid[i + m] * 256 + tid] = ev;
            acc += xv[m];
            float df = ev - xv[m];
            lsum += df * df;
        }
    }
    for (; i < len; ++i) {
        int row = rid[i];
        float xv = x[(size_t)row * 256 + tid];
        q_out[(size_t)row * 256 + tid] = ev;
        acc += xv;
        float df = ev - xv;
        lsum += df * df;
    }
    udw[(size_t)b * 256 + tid] = acc;
    const int lane = tid & 63, wid = tid >> 6;
    __shared__ float wsum[4];
#pragma unroll
    for (int m = 1; m < 64; m <<= 1) lsum += __shfl_xor(lsum, m);
    if (lane == 0) wsum[wid] = lsum;
    __syncthreads();
    if (tid == 0)
        lossp[b] = (double)wsum[0] + wsum[1] + wsum[2] + wsum[3];
}

// ---------------- K5: finalize new_cs (+ n) and loss (2048 partials) ----------------
__global__ __launch_bounds__(1024) void k_finalize(
    const float* __restrict__ ema_cs, const int* __restrict__ hist,
    const double* __restrict__ lossp, float* __restrict__ out)
{
    __shared__ double red[1024];
    const int tid = threadIdx.x;
    float raw = ema_cs[tid] * 0.99f + 0.01f * (float)hist[tid];
    red[tid] = (double)raw;
    __syncthreads();
    for (int s = 512; s > 0; s >>= 1) {
        if (tid < s) red[tid] += red[tid + s];
        __syncthreads();
    }
    double n = red[0];
    __syncthreads();
    float csn = (raw + 1e-5f) * (float)(n / (n + 1024.0 * 1e-5));
    out[OFF_CS + tid] = csn;
    red[tid] = lossp[tid] + lossp[tid + 1024];
    __syncthreads();
    for (int s = 512; s > 0; s >>= 1) {
        if (tid < s) red[tid] += red[tid + s];
        __syncthreads();
    }
    if (tid == 0) out[OFF_LOSS] = (float)(red[0] * 1.25 / 16777216.0);
}

// ---------------- K6: new_ema_w + updated_embed (sum unit partials) ----------------
__global__ __launch_bounds__(256) void k_ema(
    const float* __restrict__ ema_w, const float* __restrict__ udw,
    const int* __restrict__ uoffs,
    const float* __restrict__ cs_out, float* __restrict__ out)
{
    int id = blockIdx.x * 256 + threadIdx.x;
    int c = id >> 8;
    int d = id & 255;
    const int u0 = uoffs[c], u1 = uoffs[c + 1];
    float s = 0.f;
    for (int u = u0; u < u1; ++u) s += udw[(size_t)u * 256 + d];
    float nw = ema_w[id] * 0.99f + 0.01f * s;
    out[OFF_EMAW + id] = nw;
    out[OFF_UPD + id] = nw / cs_out[c];
}

extern "C" void kernel_launch(void* const* d_in, const int* in_sizes, int n_in,
                              void* d_out, int out_size, void* d_ws, size_t ws_size,
                              hipStream_t stream)
{
    const float* x      = (const float*)d_in[0];
    const float* ew     = (const float*)d_in[1];
    const float* ema_cs = (const float*)d_in[2];
    const float* ema_w  = (const float*)d_in[3];
    float* out = (float*)d_out;
    char* ws = (char*)d_ws;

    int*    hist    = (int*)(ws + WS_HIST);
    int*    gc      = (int*)(ws + WS_GC);
    int*    offs    = (int*)(ws + WS_OFFS);
    int*    curs    = (int*)(ws + WS_CURS);
    int*    uoffs   = (int*)(ws + WS_UOFFS);
    int*    units   = (int*)(ws + WS_UNITS);
    int*    idxi    = (int*)(ws + WS_IDX);
    int*    cnt     = (int*)(ws + WS_CNT);
    int*    wrows   = (int*)(ws + WS_WROWS);
    int*    rowids  = (int*)(ws + WS_ROWIDS);
    float*  sqx     = (float*)(ws + WS_SQX);
    float*  sqe     = (float*)(ws + WS_SQE);
    float*  udw     = (float*)(ws + WS_UDW);
    unsigned long long* packed = (unsigned long long*)(ws + WS_PACK);
    double* lossp   = (double*)(ws + WS_LOSSP);
    unsigned short* ebt = (unsigned short*)(ws + WS_EBT);
    int*    cand    = (int*)(ws + WS_CAND);

    hipMemsetAsync(ws, 0, 4112, stream);   // hist + gc
    hipLaunchKernelGGL(k_cvt, dim3(32), dim3(256), 0, stream, ew, ebt, sqe);
    hipLaunchKernelGGL(k_screen, dim3(NROWS / 32), dim3(256), 0, stream,
                       x, ebt, sqe, sqx, cnt, cand, idxi, out + OFF_IDX,
                       hist, wrows, gc, packed);
    hipLaunchKernelGGL(k_rescore, dim3(512), dim3(256), 0, stream,
                       x, ew, sqx, sqe, cnt, cand, wrows, gc, packed);
    hipLaunchKernelGGL(k_resolve, dim3(64), dim3(256), 0, stream,
                       wrows, gc, packed, idxi, out + OFF_IDX, hist);
    hipLaunchKernelGGL(k_prefix, dim3(1), dim3(1024), 0, stream,
                       hist, offs, curs, uoffs, units, lossp);
    hipLaunchKernelGGL(k_fill, dim3(NROWS / 256), dim3(256), 0, stream,
                       idxi, curs, rowids);
    hipLaunchKernelGGL(k_dw, dim3(2048), dim3(256), 0, stream,
                       x, ew, hist, offs, uoffs, units, rowids,
                       out + OFF_Q, udw, lossp);
    hipLaunchKernelGGL(k_finalize, dim3(1), dim3(1024), 0, stream,
                       ema_cs, hist, lossp, out);
    hipLaunchKernelGGL(k_ema, dim3(1024), dim3(256), 0, stream,
                       ema_w, udw, uoffs, out + OFF_CS, out);
}

// Round 20
// 206.191 us; speedup vs baseline: 4.2283x; 4.2283x over previous
//
#include <hip/hip_runtime.h>
#include <math.h>

#define NROWS 65536
#define D 256
#define K 1024
#define CAP 8
#define SCAP 8
#define EPS 1e-3f

// d_out offsets (floats)
#define OFF_Q     0
#define OFF_LOSS  16777216
#define OFF_IDX   16777217
#define OFF_CS    16842753
#define OFF_EMAW  16843777
#define OFF_UPD   17105921

// ws offsets (bytes)
#define WS_HIST     0          // 1024 int (memset 0, together with GC)
#define WS_GC       4096       // 4 int: [0]=worklist rows, [1]=fullscan rows
#define WS_OFFS     8192       // 1024 int
#define WS_CURS     12288      // 1024 int
#define WS_UOFFS    16384      // 1025 int (unit prefix; [1024]=total U)
#define WS_UNITS    20736      // 2048 int ((j<<10)|c)
#define WS_IDX      29184      // 65536 int
#define WS_CNT      291328     // 65536 int
#define WS_WROWS    553472     // 65536 int
#define WS_ROWIDS   815616     // 65536 int
#define WS_SQX      1077760    // 65536 f32
#define WS_SQE      1339904    // 1024 f32
#define WS_LOSSP    1344000    // 2048 double (zeroed by k_prefix)
#define WS_EBT      1360384    // 8*1024*32 ushort (bf16, k-chunk-major)
#define WS_CAND     1884672    // 65536*8 int
#define WS_UDW      3981824    // 2048*256 f32 (per-unit dw partials)
#define WS_PACK     3981824    //   alias: 65536 u64 (init by k_screen; dead before k_dw)
#define WS_FROWS    6078976    // 65536 int (fullscan rows)  ends 6341120

typedef __attribute__((ext_vector_type(8))) short short8;
typedef __attribute__((ext_vector_type(8))) unsigned short ushort8;
typedef __attribute__((ext_vector_type(4))) float f32x4;

__device__ __forceinline__ unsigned short f2b(float f) {   // RNE f32->bf16
    unsigned u = __builtin_bit_cast(unsigned, f);
    return (unsigned short)((u + 0x7fffu + ((u >> 16) & 1u)) >> 16);
}

// exact reference-order dot: single f32 acc, fmaf over k=0..255 ascending.
__device__ __forceinline__ float dot_chain(const float4* __restrict__ xr,
                                           const float4* __restrict__ er) {
#pragma clang fp contract(off)
    float acc = 0.f;
#pragma unroll
    for (int g = 0; g < 8; ++g) {
        float4 xa[8], ea[8];
#pragma unroll
        for (int m = 0; m < 8; ++m) { xa[m] = xr[g * 8 + m]; ea[m] = er[g * 8 + m]; }
#pragma unroll
        for (int m = 0; m < 8; ++m) {
            acc = __builtin_fmaf(xa[m].x, ea[m].x, acc);
            acc = __builtin_fmaf(xa[m].y, ea[m].y, acc);
            acc = __builtin_fmaf(xa[m].z, ea[m].z, acc);
            acc = __builtin_fmaf(xa[m].w, ea[m].w, acc);
        }
    }
    return acc;
}

// ---------------- K0b: codebook -> bf16 k-chunk-major [8][1024][32] + fused sqe ----------------
__global__ __launch_bounds__(256) void k_cvt(const float* __restrict__ ew,
                                             unsigned short* __restrict__ ebt,
                                             float* __restrict__ sqe)
{
#pragma clang fp contract(off)
    int t = blockIdx.x * 256 + threadIdx.x;   // 0..8191
    int code = t >> 3, kc = t & 7;
    const float4* src = (const float4*)&ew[(size_t)code * 256 + kc * 32];
    unsigned short* dst = &ebt[((size_t)kc * 1024 + code) * 32];
    float4 f[8];
#pragma unroll
    for (int j = 0; j < 8; ++j) f[j] = src[j];
#pragma unroll
    for (int j = 0; j < 8; ++j) {
        ushort4 o;
        o.x = f2b(f[j].x); o.y = f2b(f[j].y); o.z = f2b(f[j].z); o.w = f2b(f[j].w);
        *(ushort4*)&dst[j * 4] = o;
    }
    float p[16];
#pragma unroll
    for (int m = 0; m < 4; ++m) {
        p[4*m+0] = f[m].x * f[m].x + f[m+4].x * f[m+4].x;
        p[4*m+1] = f[m].y * f[m].y + f[m+4].y * f[m+4].y;
        p[4*m+2] = f[m].z * f[m].z + f[m+4].z * f[m+4].z;
        p[4*m+3] = f[m].w * f[m].w + f[m+4].w * f[m+4].w;
    }
    float V[16];
#pragma unroll
    for (int l2 = 0; l2 < 16; ++l2) {
        float q = p[l2] + __shfl_xor(p[l2], 1);
        V[l2] = q + __shfl_xor(q, 2);
    }
    float t8[8];
#pragma unroll
    for (int l2 = 0; l2 < 8; ++l2) t8[l2] = V[l2] + V[l2 + 8];
    float u4[4];
#pragma unroll
    for (int l2 = 0; l2 < 4; ++l2) u4[l2] = t8[l2] + t8[l2 + 4];
    float h = (u4[0] + u4[2]) + (u4[1] + u4[3]);
    float sq = h + __shfl_xor(h, 4);
    if (kc == 0) sqe[code] = sq;
}

// ---------------- K1: MFMA bf16 screen; running-gmin collection; 19712 B LDS ----------------
__global__ __launch_bounds__(256) void k_screen(
    const float* __restrict__ x, const unsigned short* __restrict__ ebt,
    const float* __restrict__ sqe, float* __restrict__ sqx_out,
    int* __restrict__ cnt, int* __restrict__ cand,
    int* __restrict__ idx_out, float* __restrict__ idxf_out,
    int* __restrict__ hist, int* __restrict__ wrows, int* __restrict__ gc,
    unsigned long long* __restrict__ packed, int* __restrict__ frows)
{
    __shared__ unsigned short xs[32][264];   // 16896 B
    __shared__ float red[32][4];             // 512 B
    __shared__ int lcnt[32];                 // 128 B
    __shared__ float gmin[32];               // 128 B
    __shared__ int scand_c[32][SCAP];        // 1024 B
    __shared__ float scand_s[32][SCAP];      // 1024 B

    const int tid = threadIdx.x;
    const int wn = tid >> 6;
    const int l = tid & 63;
    const int row0 = blockIdx.x * 32;

    if (tid < 32) { lcnt[tid] = 0; gmin[tid] = 3.4e38f; }

    {
        const int row = tid >> 3, kq8 = tid & 7;
        const float4* src = (const float4*)&x[(size_t)(row0 + row) * 256 + kq8 * 32];
        float4 f[8];
#pragma unroll
        for (int j = 0; j < 8; ++j) f[j] = src[j];
#pragma unroll
        for (int j = 0; j < 8; ++j) {
            ushort4 o;
            o.x = f2b(f[j].x); o.y = f2b(f[j].y); o.z = f2b(f[j].z); o.w = f2b(f[j].w);
            *(ushort4*)&xs[row][kq8 * 32 + j * 4] = o;
        }
        float p[16];
#pragma unroll
        for (int m = 0; m < 4; ++m) {
            p[4*m+0] = f[m].x * f[m].x + f[m+4].x * f[m+4].x;
            p[4*m+1] = f[m].y * f[m].y + f[m+4].y * f[m+4].y;
            p[4*m+2] = f[m].z * f[m].z + f[m+4].z * f[m+4].z;
            p[4*m+3] = f[m].w * f[m].w + f[m+4].w * f[m+4].w;
        }
        float V[16];
#pragma unroll
        for (int l2 = 0; l2 < 16; ++l2) {
            float q = p[l2] + __shfl_xor(p[l2], 1);
            V[l2] = q + __shfl_xor(q, 2);
        }
        float t8[8];
#pragma unroll
        for (int l2 = 0; l2 < 8; ++l2) t8[l2] = V[l2] + V[l2 + 8];
        float u4[4];
#pragma unroll
        for (int l2 = 0; l2 < 4; ++l2) u4[l2] = t8[l2] + t8[l2 + 4];
        float h = (u4[0] + u4[2]) + (u4[1] + u4[3]);
        float sq = h + __shfl_xor(h, 4);
        if (kq8 == 0) sqx_out[row0 + row] = sq;
    }
    __syncthreads();

#pragma unroll 1
    for (int ct = 0; ct < 4; ++ct) {
        f32x4 acc[2][4];
#pragma unroll
        for (int mt = 0; mt < 2; ++mt)
#pragma unroll
            for (int nt = 0; nt < 4; ++nt) acc[mt][nt] = (f32x4)0.f;

#pragma unroll 2
        for (int kc = 0; kc < 8; ++kc) {
            short8 a[2], b[4];
#pragma unroll
            for (int nt = 0; nt < 4; ++nt)
                b[nt] = *(const short8*)&ebt[
                    ((size_t)kc * 1024 + ct * 256 + wn * 64 + nt * 16 + (l & 15)) * 32
                    + (l >> 4) * 8];
#pragma unroll
            for (int mt = 0; mt < 2; ++mt)
                a[mt] = *(const short8*)&xs[mt * 16 + (l & 15)][kc * 32 + (l >> 4) * 8];
#pragma unroll
            for (int mt = 0; mt < 2; ++mt)
#pragma unroll
                for (int nt = 0; nt < 4; ++nt)
                    acc[mt][nt] = __builtin_amdgcn_mfma_f32_16x16x32_bf16(
                        a[mt], b[nt], acc[mt][nt], 0, 0, 0);
        }

        float sev[4];
#pragma unroll
        for (int nt = 0; nt < 4; ++nt)
            sev[nt] = sqe[ct * 256 + wn * 64 + nt * 16 + (l & 15)];

        float s_[2][16];
        float lmin[2][4];
#pragma unroll
        for (int mt = 0; mt < 2; ++mt) {
#pragma unroll
            for (int q = 0; q < 4; ++q) lmin[mt][q] = 3.4e38f;
#pragma unroll
            for (int nt = 0; nt < 4; ++nt)
#pragma unroll
                for (int q = 0; q < 4; ++q) {
                    float sv = sev[nt] - 2.0f * acc[mt][nt][q];
                    s_[mt][nt * 4 + q] = sv;
                    lmin[mt][q] = fminf(lmin[mt][q], sv);
                }
        }
#pragma unroll
        for (int mt = 0; mt < 2; ++mt)
#pragma unroll
            for (int q = 0; q < 4; ++q) {
                float v = lmin[mt][q];
#pragma unroll
                for (int m = 1; m < 16; m <<= 1) v = fminf(v, __shfl_xor(v, m));
                if ((l & 15) == 0) red[mt * 16 + (l >> 4) * 4 + q][wn] = v;
            }
        __syncthreads();
        // update running global row-min THROUGH this ct
        if (tid < 32)
            gmin[tid] = fminf(gmin[tid],
                              fminf(fminf(red[tid][0], red[tid][1]),
                                    fminf(red[tid][2], red[tid][3])));
        __syncthreads();   // gmin visible to all before collection
        // collect against RUNNING global min (superset of final window;
        // kills the per-ct-local inflation that overflowed SCAP)
#pragma unroll
        for (int mt = 0; mt < 2; ++mt)
#pragma unroll
            for (int q = 0; q < 4; ++q) {
                const int rw = mt * 16 + (l >> 4) * 4 + q;
                const float rm = gmin[rw] + EPS;
                if (__any(lmin[mt][q] <= rm)) {
#pragma unroll
                    for (int nt = 0; nt < 4; ++nt) {
                        float s = s_[mt][nt * 4 + q];
                        if (s <= rm) {
                            int c = ct * 256 + wn * 64 + nt * 16 + (l & 15);
                            int slot = atomicAdd(&lcnt[rw], 1);
                            if (slot < SCAP) { scand_c[rw][slot] = c; scand_s[rw][slot] = s; }
                        }
                    }
                }
            }
        __syncthreads();
    }
    if (tid < 32) {
        const int row = row0 + tid;
        const int m = lcnt[tid];
        if (m > SCAP) {
            // rare overflow: bounded-cost exact full scan kernel handles it
            cnt[row] = CAP + 1;
            int p1 = atomicAdd(&gc[1], 1);
            frows[p1] = row;
        } else {
            const float thr = gmin[tid] + EPS;
            int n = 0;
            int keep[CAP];
            for (int j = 0; j < m; ++j) {
                if (scand_s[tid][j] <= thr) {
                    if (n < CAP) keep[n] = scand_c[tid][j];
                    ++n;
                }
            }
            cnt[row] = n;
            if (n == 1) {
                idx_out[row] = keep[0];
                idxf_out[row] = (float)keep[0];
                atomicAdd(&hist[keep[0]], 1);
            } else {
                packed[row] = ~0ULL;
                int p0 = atomicAdd(&gc[0], 1);
                wrows[p0] = row;
                for (int s = 0; s < n; ++s)
                    cand[(size_t)row * CAP + s] = keep[s];
            }
        }
    }
}

// ---------------- K1b: pair-per-lane exact rescore -> packed atomicMin ----------------
__global__ __launch_bounds__(256) void k_rescore(
    const float* __restrict__ x, const float* __restrict__ ew,
    const float* __restrict__ sqx, const float* __restrict__ sqe,
    const int* __restrict__ cnt, const int* __restrict__ cand,
    const int* __restrict__ wrows, const int* __restrict__ gc,
    unsigned long long* __restrict__ packed)
{
#pragma clang fp contract(off)
    const int nw = gc[0];
    const int total = nw * CAP;
    for (int i = blockIdx.x * 256 + threadIdx.x; i < total; i += gridDim.x * 256) {
        const int row = wrows[i >> 3];
        const int slot = i & (CAP - 1);
        const int n = cnt[row];
        if (n < 2 || n > CAP || slot >= n) continue;   // overflow handled by k_fullscan
        const float sxr = sqx[row];
        const float4* xr = (const float4*)&x[(size_t)row * 256];
        const int c = cand[(size_t)row * CAP + slot];
        float acc = dot_chain(xr, (const float4*)&ew[(size_t)c * 256]);
        float d = (sxr - 2.0f * acc) + sqe[c];
        unsigned long long key =
            ((unsigned long long)__builtin_bit_cast(unsigned, d) << 32) | (unsigned)c;
        atomicMin(&packed[row], key);
    }
}

// ---------------- K1b2: bounded exact full scan for overflow rows (1 block/row) ----------------
__global__ __launch_bounds__(256) void k_fullscan(
    const float* __restrict__ x, const float* __restrict__ ew,
    const float* __restrict__ sqx, const float* __restrict__ sqe,
    const int* __restrict__ frows, const int* __restrict__ gc,
    int* __restrict__ idx_out, float* __restrict__ idxf_out, int* __restrict__ hist)
{
#pragma clang fp contract(off)
    __shared__ float bv[4]; __shared__ int bi[4];
    const int nf = gc[1];
    const int tid = threadIdx.x;
    for (int f = blockIdx.x; f < nf; f += gridDim.x) {
        const int row = frows[f];
        const float sxr = sqx[row];
        const float4* xr = (const float4*)&x[(size_t)row * 256];
        float bd = 3.4e38f; int bc = 0x7fffffff;
        for (int c = tid; c < K; c += 256) {
            float acc = dot_chain(xr, (const float4*)&ew[(size_t)c * 256]);
            float d = (sxr - 2.0f * acc) + sqe[c];
            if (d < bd || (d == bd && c < bc)) { bd = d; bc = c; }
        }
#pragma unroll
        for (int m = 1; m < 64; m <<= 1) {
            float od = __shfl_xor(bd, m); int oc = __shfl_xor(bc, m);
            if (od < bd || (od == bd && oc < bc)) { bd = od; bc = oc; }
        }
        if ((tid & 63) == 0) { bv[tid >> 6] = bd; bi[tid >> 6] = bc; }
        __syncthreads();
        if (tid == 0) {
            float d0 = bv[0]; int c0 = bi[0];
            for (int w = 1; w < 4; ++w)
                if (bv[w] < d0 || (bv[w] == d0 && bi[w] < c0)) { d0 = bv[w]; c0 = bi[w]; }
            idx_out[row] = c0;
            idxf_out[row] = (float)c0;
            atomicAdd(&hist[c0], 1);
        }
        __syncthreads();
    }
}

// ---------------- K1c: resolve worklist rows -> idx + hist ----------------
__global__ __launch_bounds__(256) void k_resolve(
    const int* __restrict__ wrows, const int* __restrict__ gc,
    const unsigned long long* __restrict__ packed,
    int* __restrict__ idx_out, float* __restrict__ idxf_out, int* __restrict__ hist)
{
    const int nw = gc[0];
    for (int i = blockIdx.x * 256 + threadIdx.x; i < nw; i += gridDim.x * 256) {
        const int row = wrows[i];
        const int c = (int)(packed[row] & 0xffffffffu);
        idx_out[row] = c;
        idxf_out[row] = (float)c;
        atomicAdd(&hist[c], 1);
    }
}

// ---------------- K2: prefix sums (codes + work units) + zero loss partials ----------------
__global__ __launch_bounds__(1024) void k_prefix(
    const int* __restrict__ hist, int* __restrict__ offs, int* __restrict__ curs,
    int* __restrict__ uoffs, int* __restrict__ units, double* __restrict__ lossp)
{
    __shared__ int tmp[1024];
    const int tid = threadIdx.x;
    const int h = hist[tid];
    tmp[tid] = h;
    __syncthreads();
    for (int off = 1; off < 1024; off <<= 1) {
        int v = (tid >= off) ? tmp[tid - off] : 0;
        __syncthreads();
        tmp[tid] += v;
        __syncthreads();
    }
    int ex = tmp[tid] - h;
    offs[tid] = ex;
    curs[tid] = ex;
    __syncthreads();
    const int uc = (h + 63) >> 6;
    tmp[tid] = uc;
    __syncthreads();
    for (int off = 1; off < 1024; off <<= 1) {
        int v = (tid >= off) ? tmp[tid - off] : 0;
        __syncthreads();
        tmp[tid] += v;
        __syncthreads();
    }
    const int uex = tmp[tid] - uc;
    uoffs[tid] = uex;
    if (tid == 1023) uoffs[1024] = tmp[1023];
    lossp[tid] = 0.0;
    lossp[tid + 1024] = 0.0;
    for (int j = 0; j < uc; ++j)
        units[uex + j] = (j << 10) | tid;
}

// ---------------- K3: fill row-id bins ----------------
__global__ __launch_bounds__(256) void k_fill(
    const int* __restrict__ idx_in, int* __restrict__ curs, int* __restrict__ rowids)
{
    int r = blockIdx.x * 256 + threadIdx.x;
    int c = idx_in[r];
    int slot = atomicAdd(&curs[c], 1);
    rowids[slot] = r;
}

// ---------------- K4: per-UNIT dw partial, 8-wide batched gather ----------------
__global__ __launch_bounds__(256) void k_dw(
    const float* __restrict__ x, const float* __restrict__ ew,
    const int* __restrict__ hist, const int* __restrict__ offs,
    const int* __restrict__ uoffs, const int* __restrict__ units,
    const int* __restrict__ rowids,
    float* __restrict__ q_out, float* __restrict__ udw, double* __restrict__ lossp)
{
    const int U = uoffs[1024];
    const int b = blockIdx.x;
    if (b >= U) return;
    const int u = units[b];
    const int c = u & 1023;
    const int j = u >> 10;
    const int tid = threadIdx.x;
    const int n = hist[c];
    const int start = j << 6;
    const int len = min(64, n - start);
    const int base = offs[c] + start;
    __shared__ int rid[64];
    if (tid < 64 && tid < len) rid[tid] = rowids[base + tid];
    __syncthreads();
    const float ev = ew[(size_t)c * 256 + tid];
    float acc = 0.f;
    float lsum = 0.f;
    int i = 0;
    for (; i + 8 <= len; i += 8) {
        float xv[8];
#pragma unroll
        for (int m = 0; m < 8; ++m)
            xv[m] = x[(size_t)rid[i + m] * 256 + tid];
#pragma unroll
        for (int m = 0; m < 8; ++m) {
            q_out[(size_t)rid[i + m] * 256 + tid] = ev;
            acc += xv[m];
            float df = ev - xv[m];
            lsum += df * df;
        }
    }
    for (; i < len; ++i) {
        int row = rid[i];
        float xv = x[(size_t)row * 256 + tid];
        q_out[(size_t)row * 256 + tid] = ev;
        acc += xv;
        float df = ev - xv;
        lsum += df * df;
    }
    udw[(size_t)b * 256 + tid] = acc;
    const int lane = tid & 63, wid = tid >> 6;
    __shared__ float wsum[4];
#pragma unroll
    for (int m = 1; m < 64; m <<= 1) lsum += __shfl_xor(lsum, m);
    if (lane == 0) wsum[wid] = lsum;
    __syncthreads();
    if (tid == 0)
        lossp[b] = (double)wsum[0] + wsum[1] + wsum[2] + wsum[3];
}

// ---------------- K5: finalize new_cs (+ n) and loss (2048 partials) ----------------
__global__ __launch_bounds__(1024) void k_finalize(
    const float* __restrict__ ema_cs, const int* __restrict__ hist,
    const double* __restrict__ lossp, float* __restrict__ out)
{
    __shared__ double red[1024];
    const int tid = threadIdx.x;
    float raw = ema_cs[tid] * 0.99f + 0.01f * (float)hist[tid];
    red[tid] = (double)raw;
    __syncthreads();
    for (int s = 512; s > 0; s >>= 1) {
        if (tid < s) red[tid] += red[tid + s];
        __syncthreads();
    }
    double n = red[0];
    __syncthreads();
    float csn = (raw + 1e-5f) * (float)(n / (n + 1024.0 * 1e-5));
    out[OFF_CS + tid] = csn;
    red[tid] = lossp[tid] + lossp[tid + 1024];
    __syncthreads();
    for (int s = 512; s > 0; s >>= 1) {
        if (tid < s) red[tid] += red[tid + s];
        __syncthreads();
    }
    if (tid == 0) out[OFF_LOSS] = (float)(red[0] * 1.25 / 16777216.0);
}

// ---------------- K6: new_ema_w + updated_embed (sum unit partials) ----------------
__global__ __launch_bounds__(256) void k_ema(
    const float* __restrict__ ema_w, const float* __restrict__ udw,
    const int* __restrict__ uoffs,
    const float* __restrict__ cs_out, float* __restrict__ out)
{
    int id = blockIdx.x * 256 + threadIdx.x;
    int c = id >> 8;
    int d = id & 255;
    const int u0 = uoffs[c], u1 = uoffs[c + 1];
    float s = 0.f;
    for (int u = u0; u < u1; ++u) s += udw[(size_t)u * 256 + d];
    float nw = ema_w[id] * 0.99f + 0.01f * s;
    out[OFF_EMAW + id] = nw;
    out[OFF_UPD + id] = nw / cs_out[c];
}

extern "C" void kernel_launch(void* const* d_in, const int* in_sizes, int n_in,
                              void* d_out, int out_size, void* d_ws, size_t ws_size,
                              hipStream_t stream)
{
    const float* x      = (const float*)d_in[0];
    const float* ew     = (const float*)d_in[1];
    const float* ema_cs = (const float*)d_in[2];
    const float* ema_w  = (const float*)d_in[3];
    float* out = (float*)d_out;
    char* ws = (char*)d_ws;

    int*    hist    = (int*)(ws + WS_HIST);
    int*    gc      = (int*)(ws + WS_GC);
    int*    offs    = (int*)(ws + WS_OFFS);
    int*    curs    = (int*)(ws + WS_CURS);
    int*    uoffs   = (int*)(ws + WS_UOFFS);
    int*    units   = (int*)(ws + WS_UNITS);
    int*    idxi    = (int*)(ws + WS_IDX);
    int*    cnt     = (int*)(ws + WS_CNT);
    int*    wrows   = (int*)(ws + WS_WROWS);
    int*    rowids  = (int*)(ws + WS_ROWIDS);
    float*  sqx     = (float*)(ws + WS_SQX);
    float*  sqe     = (float*)(ws + WS_SQE);
    float*  udw     = (float*)(ws + WS_UDW);
    unsigned long long* packed = (unsigned long long*)(ws + WS_PACK);
    double* lossp   = (double*)(ws + WS_LOSSP);
    unsigned short* ebt = (unsigned short*)(ws + WS_EBT);
    int*    cand    = (int*)(ws + WS_CAND);
    int*    frows   = (int*)(ws + WS_FROWS);

    hipMemsetAsync(ws, 0, 4112, stream);   // hist + gc
    hipLaunchKernelGGL(k_cvt, dim3(32), dim3(256), 0, stream, ew, ebt, sqe);
    hipLaunchKernelGGL(k_screen, dim3(NROWS / 32), dim3(256), 0, stream,
                       x, ebt, sqe, sqx, cnt, cand, idxi, out + OFF_IDX,
                       hist, wrows, gc, packed, frows);
    hipLaunchKernelGGL(k_rescore, dim3(512), dim3(256), 0, stream,
                       x, ew, sqx, sqe, cnt, cand, wrows, gc, packed);
    hipLaunchKernelGGL(k_fullscan, dim3(64), dim3(256), 0, stream,
                       x, ew, sqx, sqe, frows, gc, idxi, out + OFF_IDX, hist);
    hipLaunchKernelGGL(k_resolve, dim3(64), dim3(256), 0, stream,
                       wrows, gc, packed, idxi, out + OFF_IDX, hist);
    hipLaunchKernelGGL(k_prefix, dim3(1), dim3(1024), 0, stream,
                       hist, offs, curs, uoffs, units, lossp);
    hipLaunchKernelGGL(k_fill, dim3(NROWS / 256), dim3(256), 0, stream,
                       idxi, curs, rowids);
    hipLaunchKernelGGL(k_dw, dim3(2048), dim3(256), 0, stream,
                       x, ew, hist, offs, uoffs, units, rowids,
                       out + OFF_Q, udw, lossp);
    hipLaunchKernelGGL(k_finalize, dim3(1), dim3(1024), 0, stream,
                       ema_cs, hist, lossp, out);
    hipLaunchKernelGGL(k_ema, dim3(1024), dim3(256), 0, stream,
                       ema_w, udw, uoffs, out + OFF_CS, out);
}

// Round 21
// 172.104 us; speedup vs baseline: 5.0657x; 1.1981x over previous
//
#include <hip/hip_runtime.h>
#include <math.h>

#define NROWS 65536
#define D 256
#define K 1024
#define CAP 8
#define SCAP 16
#define EPS 1e-3f

// d_out offsets (floats)
#define OFF_Q     0
#define OFF_LOSS  16777216
#define OFF_IDX   16777217
#define OFF_CS    16842753
#define OFF_EMAW  16843777
#define OFF_UPD   17105921

// ws offsets (bytes)
#define WS_HIST     0          // 1024 int (memset 0, together with GC)
#define WS_GC       4096       // 4 int
#define WS_OFFS     8192       // 1024 int
#define WS_CURS     12288      // 1024 int
#define WS_UOFFS    16384      // 1025 int (unit prefix; [1024]=total U)
#define WS_UNITS    20736      // 2048 int ((j<<10)|c)
#define WS_IDX      29184      // 65536 int
#define WS_CNT      291328     // 65536 int
#define WS_WROWS    553472     // 65536 int
#define WS_ROWIDS   815616     // 65536 int
#define WS_SQX      1077760    // 65536 f32
#define WS_SQE      1339904    // 1024 f32
#define WS_LOSSP    1344000    // 2048 double (zeroed by k_prefix)
#define WS_EBT      1360384    // 8*1024*32 ushort (bf16, k-chunk-major)
#define WS_CAND     1884672    // 65536*8 int
#define WS_UDW      3981824    // 2048*256 f32 (per-unit dw partials)
#define WS_PACK     3981824    //   alias: 65536 u64 (init by k_screen; dead before k_dw)
// ends 6078976

typedef __attribute__((ext_vector_type(8))) short short8;
typedef __attribute__((ext_vector_type(8))) unsigned short ushort8;
typedef __attribute__((ext_vector_type(4))) float f32x4;

__device__ __forceinline__ unsigned short f2b(float f) {   // RNE f32->bf16
    unsigned u = __builtin_bit_cast(unsigned, f);
    return (unsigned short)((u + 0x7fffu + ((u >> 16) & 1u)) >> 16);
}

// exact reference-order dot: single f32 acc, fmaf over k=0..255 ascending.
__device__ __forceinline__ float dot_chain(const float4* __restrict__ xr,
                                           const float4* __restrict__ er) {
#pragma clang fp contract(off)
    float acc = 0.f;
#pragma unroll
    for (int g = 0; g < 8; ++g) {
        float4 xa[8], ea[8];
#pragma unroll
        for (int m = 0; m < 8; ++m) { xa[m] = xr[g * 8 + m]; ea[m] = er[g * 8 + m]; }
#pragma unroll
        for (int m = 0; m < 8; ++m) {
            acc = __builtin_fmaf(xa[m].x, ea[m].x, acc);
            acc = __builtin_fmaf(xa[m].y, ea[m].y, acc);
            acc = __builtin_fmaf(xa[m].z, ea[m].z, acc);
            acc = __builtin_fmaf(xa[m].w, ea[m].w, acc);
        }
    }
    return acc;
}

// ---------------- K0b: codebook -> bf16 k-chunk-major [8][1024][32] + fused sqe ----------------
__global__ __launch_bounds__(256) void k_cvt(const float* __restrict__ ew,
                                             unsigned short* __restrict__ ebt,
                                             float* __restrict__ sqe)
{
#pragma clang fp contract(off)
    int t = blockIdx.x * 256 + threadIdx.x;   // 0..8191
    int code = t >> 3, kc = t & 7;
    const float4* src = (const float4*)&ew[(size_t)code * 256 + kc * 32];
    unsigned short* dst = &ebt[((size_t)kc * 1024 + code) * 32];
    float4 f[8];
#pragma unroll
    for (int j = 0; j < 8; ++j) f[j] = src[j];
#pragma unroll
    for (int j = 0; j < 8; ++j) {
        ushort4 o;
        o.x = f2b(f[j].x); o.y = f2b(f[j].y); o.z = f2b(f[j].z); o.w = f2b(f[j].w);
        *(ushort4*)&dst[j * 4] = o;
    }
    float p[16];
#pragma unroll
    for (int m = 0; m < 4; ++m) {
        p[4*m+0] = f[m].x * f[m].x + f[m+4].x * f[m+4].x;
        p[4*m+1] = f[m].y * f[m].y + f[m+4].y * f[m+4].y;
        p[4*m+2] = f[m].z * f[m].z + f[m+4].z * f[m+4].z;
        p[4*m+3] = f[m].w * f[m].w + f[m+4].w * f[m+4].w;
    }
    float V[16];
#pragma unroll
    for (int l2 = 0; l2 < 16; ++l2) {
        float q = p[l2] + __shfl_xor(p[l2], 1);
        V[l2] = q + __shfl_xor(q, 2);
    }
    float t8[8];
#pragma unroll
    for (int l2 = 0; l2 < 8; ++l2) t8[l2] = V[l2] + V[l2 + 8];
    float u4[4];
#pragma unroll
    for (int l2 = 0; l2 < 4; ++l2) u4[l2] = t8[l2] + t8[l2 + 4];
    float h = (u4[0] + u4[2]) + (u4[1] + u4[3]);
    float sq = h + __shfl_xor(h, 4);
    if (kc == 0) sqe[code] = sq;
}

// ---------------- K1: MFMA bf16 screen, 32 rows / 256 thr / 4 waves ----------------
__global__ __launch_bounds__(256) void k_screen(
    const float* __restrict__ x, const unsigned short* __restrict__ ebt,
    const float* __restrict__ sqe, float* __restrict__ sqx_out,
    int* __restrict__ cnt, int* __restrict__ cand,
    int* __restrict__ idx_out, float* __restrict__ idxf_out,
    int* __restrict__ hist, int* __restrict__ wrows, int* __restrict__ gc,
    unsigned long long* __restrict__ packed)
{
    __shared__ unsigned short xs[32][264];
    __shared__ float red[32][4];
    __shared__ int lcnt[32];
    __shared__ float gmin[32];
    __shared__ int scand_c[32][SCAP];
    __shared__ float scand_s[32][SCAP];

    const int tid = threadIdx.x;
    const int wn = tid >> 6;
    const int l = tid & 63;
    const int row0 = blockIdx.x * 32;

    if (tid < 32) { lcnt[tid] = 0; gmin[tid] = 3.4e38f; }

    {
        const int row = tid >> 3, kq8 = tid & 7;
        const float4* src = (const float4*)&x[(size_t)(row0 + row) * 256 + kq8 * 32];
        float4 f[8];
#pragma unroll
        for (int j = 0; j < 8; ++j) f[j] = src[j];
#pragma unroll
        for (int j = 0; j < 8; ++j) {
            ushort4 o;
            o.x = f2b(f[j].x); o.y = f2b(f[j].y); o.z = f2b(f[j].z); o.w = f2b(f[j].w);
            *(ushort4*)&xs[row][kq8 * 32 + j * 4] = o;
        }
        float p[16];
#pragma unroll
        for (int m = 0; m < 4; ++m) {
            p[4*m+0] = f[m].x * f[m].x + f[m+4].x * f[m+4].x;
            p[4*m+1] = f[m].y * f[m].y + f[m+4].y * f[m+4].y;
            p[4*m+2] = f[m].z * f[m].z + f[m+4].z * f[m+4].z;
            p[4*m+3] = f[m].w * f[m].w + f[m+4].w * f[m+4].w;
        }
        float V[16];
#pragma unroll
        for (int l2 = 0; l2 < 16; ++l2) {
            float q = p[l2] + __shfl_xor(p[l2], 1);
            V[l2] = q + __shfl_xor(q, 2);
        }
        float t8[8];
#pragma unroll
        for (int l2 = 0; l2 < 8; ++l2) t8[l2] = V[l2] + V[l2 + 8];
        float u4[4];
#pragma unroll
        for (int l2 = 0; l2 < 4; ++l2) u4[l2] = t8[l2] + t8[l2 + 4];
        float h = (u4[0] + u4[2]) + (u4[1] + u4[3]);
        float sq = h + __shfl_xor(h, 4);
        if (kq8 == 0) sqx_out[row0 + row] = sq;
    }
    __syncthreads();

#pragma unroll 1
    for (int ct = 0; ct < 4; ++ct) {
        f32x4 acc[2][4];
#pragma unroll
        for (int mt = 0; mt < 2; ++mt)
#pragma unroll
            for (int nt = 0; nt < 4; ++nt) acc[mt][nt] = (f32x4)0.f;

#pragma unroll 2
        for (int kc = 0; kc < 8; ++kc) {
            short8 a[2], b[4];
#pragma unroll
            for (int nt = 0; nt < 4; ++nt)
                b[nt] = *(const short8*)&ebt[
                    ((size_t)kc * 1024 + ct * 256 + wn * 64 + nt * 16 + (l & 15)) * 32
                    + (l >> 4) * 8];
#pragma unroll
            for (int mt = 0; mt < 2; ++mt)
                a[mt] = *(const short8*)&xs[mt * 16 + (l & 15)][kc * 32 + (l >> 4) * 8];
#pragma unroll
            for (int mt = 0; mt < 2; ++mt)
#pragma unroll
                for (int nt = 0; nt < 4; ++nt)
                    acc[mt][nt] = __builtin_amdgcn_mfma_f32_16x16x32_bf16(
                        a[mt], b[nt], acc[mt][nt], 0, 0, 0);
        }

        float sev[4];
#pragma unroll
        for (int nt = 0; nt < 4; ++nt)
            sev[nt] = sqe[ct * 256 + wn * 64 + nt * 16 + (l & 15)];

        // s computed ONCE into registers; per-(mt,q) local min reused below
        float s_[2][16];
        float lmin[2][4];
#pragma unroll
        for (int mt = 0; mt < 2; ++mt) {
#pragma unroll
            for (int q = 0; q < 4; ++q) lmin[mt][q] = 3.4e38f;
#pragma unroll
            for (int nt = 0; nt < 4; ++nt)
#pragma unroll
                for (int q = 0; q < 4; ++q) {
                    float sv = sev[nt] - 2.0f * acc[mt][nt][q];
                    s_[mt][nt * 4 + q] = sv;
                    lmin[mt][q] = fminf(lmin[mt][q], sv);
                }
        }
#pragma unroll
        for (int mt = 0; mt < 2; ++mt)
#pragma unroll
            for (int q = 0; q < 4; ++q) {
                float v = lmin[mt][q];
#pragma unroll
                for (int m = 1; m < 16; m <<= 1) v = fminf(v, __shfl_xor(v, m));
                if ((l & 15) == 0) red[mt * 16 + (l >> 4) * 4 + q][wn] = v;
            }
        __syncthreads();
        if (tid < 32)
            gmin[tid] = fminf(gmin[tid],
                              fminf(fminf(red[tid][0], red[tid][1]),
                                    fminf(red[tid][2], red[tid][3])));
        // collection: wave-skip when no lane has a hit for these 4 rows
#pragma unroll
        for (int mt = 0; mt < 2; ++mt)
#pragma unroll
            for (int q = 0; q < 4; ++q) {
                const int rw = mt * 16 + (l >> 4) * 4 + q;
                const float rm = fminf(fminf(red[rw][0], red[rw][1]),
                                       fminf(red[rw][2], red[rw][3])) + EPS;
                if (__any(lmin[mt][q] <= rm)) {
#pragma unroll
                    for (int nt = 0; nt < 4; ++nt) {
                        float s = s_[mt][nt * 4 + q];
                        if (s <= rm) {
                            int c = ct * 256 + wn * 64 + nt * 16 + (l & 15);
                            int slot = atomicAdd(&lcnt[rw], 1);
                            if (slot < SCAP) { scand_c[rw][slot] = c; scand_s[rw][slot] = s; }
                        }
                    }
                }
            }
        __syncthreads();
    }
    if (tid < 32) {
        const int row = row0 + tid;
        const int m = lcnt[tid];
        if (m > SCAP) {
            cnt[row] = CAP + 1;
            packed[row] = ~0ULL;
            int p0 = atomicAdd(&gc[0], 1);
            wrows[p0] = row;
        } else {
            const float thr = gmin[tid] + EPS;
            int n = 0;
            int keep[CAP];
            for (int j = 0; j < m; ++j) {
                if (scand_s[tid][j] <= thr) {
                    if (n < CAP) keep[n] = scand_c[tid][j];
                    ++n;
                }
            }
            cnt[row] = n;
            if (n == 1) {
                idx_out[row] = keep[0];
                idxf_out[row] = (float)keep[0];
                atomicAdd(&hist[keep[0]], 1);
            } else {
                packed[row] = ~0ULL;
                int p0 = atomicAdd(&gc[0], 1);
                wrows[p0] = row;
                const int mm = n < CAP ? n : CAP;
                for (int s = 0; s < mm; ++s)
                    cand[(size_t)row * CAP + s] = keep[s];
            }
        }
    }
}

// ---------------- K1b: pair-per-lane exact rescore -> packed atomicMin ----------------
__global__ __launch_bounds__(256) void k_rescore(
    const float* __restrict__ x, const float* __restrict__ ew,
    const float* __restrict__ sqx, const float* __restrict__ sqe,
    const int* __restrict__ cnt, const int* __restrict__ cand,
    const int* __restrict__ wrows, const int* __restrict__ gc,
    unsigned long long* __restrict__ packed)
{
#pragma clang fp contract(off)
    const int nw = gc[0];
    const int total = nw * CAP;
    for (int i = blockIdx.x * 256 + threadIdx.x; i < total; i += gridDim.x * 256) {
        const int row = wrows[i >> 3];
        const int slot = i & (CAP - 1);
        const int n = cnt[row];
        const float sxr = sqx[row];
        const float4* xr = (const float4*)&x[(size_t)row * 256];
        if (n >= 2 && n <= CAP) {
            if (slot >= n) continue;
            const int c = cand[(size_t)row * CAP + slot];
            float acc = dot_chain(xr, (const float4*)&ew[(size_t)c * 256]);
            float d = (sxr - 2.0f * acc) + sqe[c];
            unsigned long long key =
                ((unsigned long long)__builtin_bit_cast(unsigned, d) << 32) | (unsigned)c;
            atomicMin(&packed[row], key);
        } else {
            float bd = 3.4e38f; int bc = 0x7fffffff;
            for (int c = slot; c < K; c += CAP) {
                float acc = dot_chain(xr, (const float4*)&ew[(size_t)c * 256]);
                float d = (sxr - 2.0f * acc) + sqe[c];
                if (d < bd || (d == bd && c < bc)) { bd = d; bc = c; }
            }
            unsigned long long key =
                ((unsigned long long)__builtin_bit_cast(unsigned, bd) << 32) | (unsigned)bc;
            atomicMin(&packed[row], key);
        }
    }
}

// ---------------- K1c: resolve worklist rows -> idx + hist ----------------
__global__ __launch_bounds__(256) void k_resolve(
    const int* __restrict__ wrows, const int* __restrict__ gc,
    const unsigned long long* __restrict__ packed,
    int* __restrict__ idx_out, float* __restrict__ idxf_out, int* __restrict__ hist)
{
    const int nw = gc[0];
    for (int i = blockIdx.x * 256 + threadIdx.x; i < nw; i += gridDim.x * 256) {
        const int row = wrows[i];
        const int c = (int)(packed[row] & 0xffffffffu);
        idx_out[row] = c;
        idxf_out[row] = (float)c;
        atomicAdd(&hist[c], 1);
    }
}

// ---------------- K2: prefix sums (codes + work units) + zero loss partials ----------------
__global__ __launch_bounds__(1024) void k_prefix(
    const int* __restrict__ hist, int* __restrict__ offs, int* __restrict__ curs,
    int* __restrict__ uoffs, int* __restrict__ units, double* __restrict__ lossp)
{
    __shared__ int tmp[1024];
    const int tid = threadIdx.x;
    const int h = hist[tid];
    tmp[tid] = h;
    __syncthreads();
    for (int off = 1; off < 1024; off <<= 1) {
        int v = (tid >= off) ? tmp[tid - off] : 0;
        __syncthreads();
        tmp[tid] += v;
        __syncthreads();
    }
    int ex = tmp[tid] - h;
    offs[tid] = ex;
    curs[tid] = ex;
    __syncthreads();
    const int uc = (h + 63) >> 6;
    tmp[tid] = uc;
    __syncthreads();
    for (int off = 1; off < 1024; off <<= 1) {
        int v = (tid >= off) ? tmp[tid - off] : 0;
        __syncthreads();
        tmp[tid] += v;
        __syncthreads();
    }
    const int uex = tmp[tid] - uc;
    uoffs[tid] = uex;
    if (tid == 1023) uoffs[1024] = tmp[1023];
    lossp[tid] = 0.0;
    lossp[tid + 1024] = 0.0;
    for (int j = 0; j < uc; ++j)
        units[uex + j] = (j << 10) | tid;
}

// ---------------- K3: fill row-id bins ----------------
__global__ __launch_bounds__(256) void k_fill(
    const int* __restrict__ idx_in, int* __restrict__ curs, int* __restrict__ rowids)
{
    int r = blockIdx.x * 256 + threadIdx.x;
    int c = idx_in[r];
    int slot = atomicAdd(&curs[c], 1);
    rowids[slot] = r;
}

// ---------------- K4: per-UNIT dw partial, 8-wide batched gather ----------------
__global__ __launch_bounds__(256) void k_dw(
    const float* __restrict__ x, const float* __restrict__ ew,
    const int* __restrict__ hist, const int* __restrict__ offs,
    const int* __restrict__ uoffs, const int* __restrict__ units,
    const int* __restrict__ rowids,
    float* __restrict__ q_out, float* __restrict__ udw, double* __restrict__ lossp)
{
    const int U = uoffs[1024];
    const int b = blockIdx.x;
    if (b >= U) return;
    const int u = units[b];
    const int c = u & 1023;
    const int j = u >> 10;
    const int tid = threadIdx.x;
    const int n = hist[c];
    const int start = j << 6;
    const int len = min(64, n - start);
    const int base = offs[c] + start;
    __shared__ int rid[64];
    if (tid < 64 && tid < len) rid[tid] = rowids[base + tid];
    __syncthreads();
    const float ev = ew[(size_t)c * 256 + tid];
    float acc = 0.f;
    float lsum = 0.f;
    int i = 0;
    for (; i + 8 <= len; i += 8) {
        float xv[8];
#pragma unroll
        for (int m = 0; m < 8; ++m)
            xv[m] = x[(size_t)rid[i + m] * 256 + tid];
#pragma unroll
        for (int m = 0; m < 8; ++m) {
            q_out[(size_t)rid[i + m] * 256 + tid] = ev;
            acc += xv[m];
            float df = ev - xv[m];
            lsum += df * df;
        }
    }
    for (; i < len; ++i) {
        int row = rid[i];
        float xv = x[(size_t)row * 256 + tid];
        q_out[(size_t)row * 256 + tid] = ev;
        acc += xv;
        float df = ev - xv;
        lsum += df * df;
    }
    udw[(size_t)b * 256 + tid] = acc;
    const int lane = tid & 63, wid = tid >> 6;
    __shared__ float wsum[4];
#pragma unroll
    for (int m = 1; m < 64; m <<= 1) lsum += __shfl_xor(lsum, m);
    if (lane == 0) wsum[wid] = lsum;
    __syncthreads();
    if (tid == 0)
        lossp[b] = (double)wsum[0] + wsum[1] + wsum[2] + wsum[3];
}

// ---------------- K5: finalize new_cs (+ n) and loss (2048 partials) ----------------
__global__ __launch_bounds__(1024) void k_finalize(
    const float* __restrict__ ema_cs, const int* __restrict__ hist,
    const double* __restrict__ lossp, float* __restrict__ out)
{
    __shared__ double red[1024];
    const int tid = threadIdx.x;
    float raw = ema_cs[tid] * 0.99f + 0.01f * (float)hist[tid];
    red[tid] = (double)raw;
    __syncthreads();
    for (int s = 512; s > 0; s >>= 1) {
        if (tid < s) red[tid] += red[tid + s];
        __syncthreads();
    }
    double n = red[0];
    __syncthreads();
    float csn = (raw + 1e-5f) * (float)(n / (n + 1024.0 * 1e-5));
    out[OFF_CS + tid] = csn;
    red[tid] = lossp[tid] + lossp[tid + 1024];
    __syncthreads();
    for (int s = 512; s > 0; s >>= 1) {
        if (tid < s) red[tid] += red[tid + s];
        __syncthreads();
    }
    if (tid == 0) out[OFF_LOSS] = (float)(red[0] * 1.25 / 16777216.0);
}

// ---------------- K6: new_ema_w + updated_embed (sum unit partials) ----------------
__global__ __launch_bounds__(256) void k_ema(
    const float* __restrict__ ema_w, const float* __restrict__ udw,
    const int* __restrict__ uoffs,
    const float* __restrict__ cs_out, float* __restrict__ out)
{
    int id = blockIdx.x * 256 + threadIdx.x;
    int c = id >> 8;
    int d = id & 255;
    const int u0 = uoffs[c], u1 = uoffs[c + 1];
    float s = 0.f;
    for (int u = u0; u < u1; ++u) s += udw[(size_t)u * 256 + d];
    float nw = ema_w[id] * 0.99f + 0.01f * s;
    out[OFF_EMAW + id] = nw;
    out[OFF_UPD + id] = nw / cs_out[c];
}

extern "C" void kernel_launch(void* const* d_in, const int* in_sizes, int n_in,
                              void* d_out, int out_size, void* d_ws, size_t ws_size,
                              hipStream_t stream)
{
    const float* x      = (const float*)d_in[0];
    const float* ew     = (const float*)d_in[1];
    const float* ema_cs = (const float*)d_in[2];
    const float* ema_w  = (const float*)d_in[3];
    float* out = (float*)d_out;
    char* ws = (char*)d_ws;

    int*    hist    = (int*)(ws + WS_HIST);
    int*    gc      = (int*)(ws + WS_GC);
    int*    offs    = (int*)(ws + WS_OFFS);
    int*    curs    = (int*)(ws + WS_CURS);
    int*    uoffs   = (int*)(ws + WS_UOFFS);
    int*    units   = (int*)(ws + WS_UNITS);
    int*    idxi    = (int*)(ws + WS_IDX);
    int*    cnt     = (int*)(ws + WS_CNT);
    int*    wrows   = (int*)(ws + WS_WROWS);
    int*    rowids  = (int*)(ws + WS_ROWIDS);
    float*  sqx     = (float*)(ws + WS_SQX);
    float*  sqe     = (float*)(ws + WS_SQE);
    float*  udw     = (float*)(ws + WS_UDW);
    unsigned long long* packed = (unsigned long long*)(ws + WS_PACK);
    double* lossp   = (double*)(ws + WS_LOSSP);
    unsigned short* ebt = (unsigned short*)(ws + WS_EBT);
    int*    cand    = (int*)(ws + WS_CAND);

    hipMemsetAsync(ws, 0, 4112, stream);   // hist + gc
    hipLaunchKernelGGL(k_cvt, dim3(32), dim3(256), 0, stream, ew, ebt, sqe);
    hipLaunchKernelGGL(k_screen, dim3(NROWS / 32), dim3(256), 0, stream,
                       x, ebt, sqe, sqx, cnt, cand, idxi, out + OFF_IDX,
                       hist, wrows, gc, packed);
    hipLaunchKernelGGL(k_rescore, dim3(512), dim3(256), 0, stream,
                       x, ew, sqx, sqe, cnt, cand, wrows, gc, packed);
    hipLaunchKernelGGL(k_resolve, dim3(64), dim3(256), 0, stream,
                       wrows, gc, packed, idxi, out + OFF_IDX, hist);
    hipLaunchKernelGGL(k_prefix, dim3(1), dim3(1024), 0, stream,
                       hist, offs, curs, uoffs, units, lossp);
    hipLaunchKernelGGL(k_fill, dim3(NROWS / 256), dim3(256), 0, stream,
                       idxi, curs, rowids);
    hipLaunchKernelGGL(k_dw, dim3(2048), dim3(256), 0, stream,
                       x, ew, hist, offs, uoffs, units, rowids,
                       out + OFF_Q, udw, lossp);
    hipLaunchKernelGGL(k_finalize, dim3(1), dim3(1024), 0, stream,
                       ema_cs, hist, lossp, out);
    hipLaunchKernelGGL(k_ema, dim3(1024), dim3(256), 0, stream,
                       ema_w, udw, uoffs, out + OFF_CS, out);
}